// Round 1
// baseline (461.978 us; speedup 1.0000x reference)
//
#include <hip/hip_runtime.h>
#include <math.h>

// Problem constants (fixed by setup_inputs)
#define M_TOK 16384   // B*T
#define DIM   256     // D (=K)
#define VOC   8192    // V (=N)

// GEMM tiling: 256x256 tile, 8 waves, 8-phase-style counted-vmcnt schedule
#define BM 256
#define BN 256
#define BK 32
#define KTILES (DIM / BK)     // 8
#define NBLK_N (VOC / BN)     // 32
#define GAP_EPS 0.01f         // rescue trigger; split-bf16 d2 err ~1e-4 << 0.01

typedef unsigned short u16;
typedef unsigned long long u64;
typedef __attribute__((ext_vector_type(8))) __bf16 bf16x8;
typedef __attribute__((ext_vector_type(4))) float f32x4;

// ---- workspace layout (float-element offsets) ------------------------------
#define WS_ESQ      0                     // [8192]
#define WS_FLAGROWS 24576                 // [16384] int
#define WS_CANDV    40960                 // [<=64][16384] f32 (32 used)
#define WS_CANDI    1089536               // [<=64][16384] int
#define WS_CANDS    2138112               // [<=64][16384] f32
#define WS_XHI      3186688               // [16384*256] bf16 (2097152 f32 slots)
#define WS_XLO      5283840
#define WS_EHI      7380992               // [8192*256] bf16 (1048576 slots)
#define WS_ELO      8429568
#define WS_COUNTS   9478144               // [8192]
#define WS_SUMS     9486336               // [8192*256]
#define WS_FLAGCNT  11583488              // [16] int
// rescueBuf [16384] u64 aliases Xhi (dead after mfma_argmin; reduce writes it)
#define WS_RESCUE   WS_XHI
#define WS_ZERO_OFF_BYTES ((size_t)WS_COUNTS * 4)
#define WS_ZERO_BYTES     ((size_t)(8192 + 2097152 + 16) * 4)

// ---- out layout (float-element offsets): quantize, codes, new_embed, new_cs, new_ea
#define OUT_Q   0
#define OUT_C   4194304
#define OUT_NE  4210688
#define OUT_NCS 6307840
#define OUT_NEA 6316032

__device__ inline u16 f2bf_rn(float x) {
    unsigned u = __float_as_uint(x);
    unsigned r = u + 0x7FFFu + ((u >> 16) & 1u);   // round-to-nearest-even
    return (u16)(r >> 16);
}
__device__ inline float bf2f(u16 u) { return __uint_as_float(((unsigned)u) << 16); }
__device__ inline unsigned f2key(float f) {          // order-preserving uint
    unsigned b = __float_as_uint(f);
    return (b & 0x80000000u) ? ~b : (b | 0x80000000u);
}

// ---------------------------------------------------------------------------
// prep: split X,E into bf16 hi/lo; compute esq from fp32 originals.
__global__ __launch_bounds__(256) void prep_kernel(
    const float* __restrict__ X, const float* __restrict__ E,
    u16* __restrict__ Xhi, u16* __restrict__ Xlo,
    u16* __restrict__ Ehi, u16* __restrict__ Elo,
    float* __restrict__ esq)
{
    int row  = blockIdx.x * 4 + (threadIdx.x >> 6);
    int lane = threadIdx.x & 63;
    bool isX = row < M_TOK;
    int r = isX ? row : row - M_TOK;
    const float* src = isX ? X + (size_t)row * DIM : E + (size_t)r * DIM;
    float4 v = ((const float4*)src)[lane];

    ushort4 h, lo;
    {
        u16 hb = f2bf_rn(v.x); h.x = hb; lo.x = f2bf_rn(v.x - bf2f(hb));
        hb = f2bf_rn(v.y); h.y = hb; lo.y = f2bf_rn(v.y - bf2f(hb));
        hb = f2bf_rn(v.z); h.z = hb; lo.z = f2bf_rn(v.z - bf2f(hb));
        hb = f2bf_rn(v.w); h.w = hb; lo.w = f2bf_rn(v.w - bf2f(hb));
    }
    u16* dh = isX ? Xhi : Ehi;
    u16* dl = isX ? Xlo : Elo;
    *(ushort4*)&dh[(size_t)r * DIM + lane * 4] = h;
    *(ushort4*)&dl[(size_t)r * DIM + lane * 4] = lo;

    if (!isX) {
        float s = v.x * v.x + v.y * v.y + v.z * v.z + v.w * v.w;
        #pragma unroll
        for (int o = 1; o < 64; o <<= 1) s += __shfl_xor(s, o, 64);
        if (lane == 0) esq[r] = s;
    }
}

// ---------------------------------------------------------------------------
// mfma_argmin, 256x256-tile 8-wave counted-vmcnt schedule (T3+T4+T5 port):
//   - LDS: 2 x 64KB double buffer; per K-tile (BK=32): Ahi|Alo|Bhi|Blo,
//     each 256 rows x 64B, XOR chunk-swizzled via pre-swizzled global source
//     (same proven pattern as before: 0 bank conflicts on ds_read_b128).
//   - per K-tile: 8 staging steps (s0,s1=Bhi, s2,s3=Blo, s4..s7=A row-subblocks
//     for phases 0..3), 4 phases x 24 MFMA. 2 prefetch loads issued per phase
//     into the other buffer; vmcnt never drains to 0 in the main loop:
//     end-of-phase ledger = vmcnt(4/5/6/3) steady state (deadline: entering
//     phase p of tile t needs s0..s4+p of t landed; barriers are raw s_barrier).
//   - setprio(1) around the MFMA cluster (T5: pays only in phase-split scheds).
__device__ __forceinline__ void gll16(const void* src, void* dst) {
    __builtin_amdgcn_global_load_lds(
        (const __attribute__((address_space(1))) unsigned int*)src,
        (__attribute__((address_space(3))) unsigned int*)dst, 16, 0, 0);
}
#define VMCNT(n) asm volatile("s_waitcnt vmcnt(" #n ")" ::: "memory")
#define LGKM0    asm volatile("s_waitcnt lgkmcnt(0)" ::: "memory")

__global__ __launch_bounds__(512, 2) void mfma_argmin_kernel(
    const u16* __restrict__ Xhi, const u16* __restrict__ Xlo,
    const u16* __restrict__ Ehi, const u16* __restrict__ Elo,
    const float* __restrict__ esq,
    float* __restrict__ candV, int* __restrict__ candI, float* __restrict__ candS)
{
    __shared__ __align__(16) char lds[131072];   // 2 x 64KB K-tile buffers

    const int tid = threadIdx.x;
    const int l = tid & 63, w = tid >> 6;
    const int wm = w >> 2, wn = w & 3;           // wave grid 2(M) x 4(N)
    const int m0 = blockIdx.x * BM, n0 = blockIdx.y * BN;

    f32x4 acc[8][4];
    #pragma unroll
    for (int i = 0; i < 8; ++i)
        #pragma unroll
        for (int j = 0; j < 4; ++j) acc[i][j] = (f32x4)0.0f;

    // ---- staging geometry (per-thread)
    const int lr = l >> 2;                          // row within 16-row group
    const int ch = (l & 3) ^ ((l >> 3) & 3);        // swizzled source chunk
    const int wa = w & 3;
    const int cA = (wa & 1) * 16 + ((wa >> 1) & 1) * 128;  // A row offset per wave
    const u16* srcB_hi = Ehi + (size_t)(n0 + w * 16 + lr) * DIM + ch * 8;
    const u16* srcB_lo = Elo + (size_t)(n0 + w * 16 + lr) * DIM + ch * 8;
    const u16* srcA    = (w < 4 ? Xhi : Xlo) + (size_t)(m0 + cA + lr) * DIM + ch * 8;
    const int dstB_hi = 32768 + w * 1024;           // Bhi region
    const int dstB_lo = 49152 + w * 1024;           // Blo region
    const int dstA    = (w < 4 ? 0 : 16384) + cA * 64;  // Ahi/Alo region

    // ---- fragment read offsets
    const int frow = l & 15, fq = l >> 4;
    const int fs = (fq ^ ((frow >> 1) & 3)) * 16;
    const int aOff = (wm * 128 + frow) * 64 + fs;           // Ahi (+16384 -> Alo)
    const int bOff = 32768 + (wn * 64 + frow) * 64 + fs;    // Bhi (+16384 -> Blo)

#define STAGE01(NB, KE) { gll16(srcB_hi + (KE),             lds + (NB) + dstB_hi); \
                          gll16(srcB_hi + (KE) + 128 * DIM, lds + (NB) + dstB_hi + 8192); }
#define STAGE23(NB, KE) { gll16(srcB_lo + (KE),             lds + (NB) + dstB_lo); \
                          gll16(srcB_lo + (KE) + 128 * DIM, lds + (NB) + dstB_lo + 8192); }
#define STAGE45(NB, KE) { gll16(srcA + (KE),                lds + (NB) + dstA); \
                          gll16(srcA + (KE) + 32 * DIM,     lds + (NB) + dstA + 2048); }
#define STAGE67(NB, KE) { gll16(srcA + (KE) + 64 * DIM,     lds + (NB) + dstA + 4096); \
                          gll16(srcA + (KE) + 96 * DIM,     lds + (NB) + dstA + 6144); }

#define READB(BUF) { const char* bb = lds + (BUF); \
    _Pragma("unroll") for (int nt = 0; nt < 4; ++nt) { \
        bh[nt] = *(const bf16x8*)(bb + bOff + nt * 1024); \
        bl[nt] = *(const bf16x8*)(bb + bOff + 16384 + nt * 1024); } }

#define PHASE(Pm, BUF, STAGE_STMT, ENDWAIT) { \
    const char* bb = lds + (BUF); \
    bf16x8 a0h = *(const bf16x8*)(bb + aOff + (2 * Pm) * 1024); \
    bf16x8 a1h = *(const bf16x8*)(bb + aOff + (2 * Pm + 1) * 1024); \
    bf16x8 a0l = *(const bf16x8*)(bb + aOff + 16384 + (2 * Pm) * 1024); \
    bf16x8 a1l = *(const bf16x8*)(bb + aOff + 16384 + (2 * Pm + 1) * 1024); \
    STAGE_STMT; \
    __builtin_amdgcn_s_barrier(); \
    LGKM0; \
    __builtin_amdgcn_s_setprio(1); \
    _Pragma("unroll") for (int nt = 0; nt < 4; ++nt) { \
        acc[2 * Pm][nt]     = __builtin_amdgcn_mfma_f32_16x16x32_bf16(a0h, bh[nt], acc[2 * Pm][nt], 0, 0, 0); \
        acc[2 * Pm + 1][nt] = __builtin_amdgcn_mfma_f32_16x16x32_bf16(a1h, bh[nt], acc[2 * Pm + 1][nt], 0, 0, 0); \
        acc[2 * Pm][nt]     = __builtin_amdgcn_mfma_f32_16x16x32_bf16(a0l, bh[nt], acc[2 * Pm][nt], 0, 0, 0); \
        acc[2 * Pm + 1][nt] = __builtin_amdgcn_mfma_f32_16x16x32_bf16(a1l, bh[nt], acc[2 * Pm + 1][nt], 0, 0, 0); \
        acc[2 * Pm][nt]     = __builtin_amdgcn_mfma_f32_16x16x32_bf16(a0h, bl[nt], acc[2 * Pm][nt], 0, 0, 0); \
        acc[2 * Pm + 1][nt] = __builtin_amdgcn_mfma_f32_16x16x32_bf16(a1h, bl[nt], acc[2 * Pm + 1][nt], 0, 0, 0); \
    } \
    __builtin_amdgcn_s_setprio(0); \
    ENDWAIT; \
    __builtin_amdgcn_s_barrier(); \
}

    bf16x8 bh[4], bl[4];

    // prologue: stage tile 0 (8 steps), guarantee s0..s4 landed (3 allowed out)
    STAGE01(0, 0); STAGE23(0, 0); STAGE45(0, 0); STAGE67(0, 0);
    VMCNT(3);
    __builtin_amdgcn_s_barrier();

    #pragma unroll 1
    for (int t = 0; t < KTILES - 1; ++t) {
        const int buf  = (t & 1) * 65536;
        const int nbuf = buf ^ 65536;
        const int ke   = (t + 1) * BK;           // next tile k element offset
        READB(buf);
        PHASE(0, buf, STAGE01(nbuf, ke), VMCNT(4));
        PHASE(1, buf, STAGE23(nbuf, ke), VMCNT(5));
        PHASE(2, buf, STAGE45(nbuf, ke), VMCNT(6));
        PHASE(3, buf, STAGE67(nbuf, ke), VMCNT(3));
    }
    // tail tile (no prefetch): drain 2 -> 1 -> 0
    READB(65536);
    PHASE(0, 65536, (void)0, VMCNT(2));
    PHASE(1, 65536, (void)0, VMCNT(1));
    PHASE(2, 65536, (void)0, VMCNT(0));
    PHASE(3, 65536, (void)0, (void)0);

    // ---- epilogue: per-row top-2 argmin of val = esq[n] - 2*dot
    __syncthreads();                     // full drain; LDS re-used below
    float* smB = (float*)lds;            // [4][256]
    int*   smI = (int*)(lds + 4096);
    float* smS = (float*)(lds + 8192);

    float eq[4];
    #pragma unroll
    for (int nt = 0; nt < 4; ++nt) eq[nt] = esq[n0 + wn * 64 + nt * 16 + frow];

    #pragma unroll
    for (int mt = 0; mt < 8; ++mt) {
        #pragma unroll
        for (int r = 0; r < 4; ++r) {
            float b = 3.4e38f, s = 3.4e38f;
            int bi = 0;
            #pragma unroll
            for (int nt = 0; nt < 4; ++nt) {
                float v = fmaf(-2.0f, acc[mt][nt][r], eq[nt]);
                int col = n0 + wn * 64 + nt * 16 + frow;
                if (v < b) { s = b; b = v; bi = col; }
                else if (v < s) s = v;
            }
            #pragma unroll
            for (int o = 1; o < 16; o <<= 1) {
                float ob = __shfl_xor(b, o, 64);
                int   oi = __shfl_xor(bi, o, 64);
                float os = __shfl_xor(s, o, 64);
                bool take = (ob < b) || (ob == b && oi < bi);
                float keep = take ? b : ob;
                b  = take ? ob : b;
                bi = take ? oi : bi;
                s  = fminf(fminf(s, os), keep);
            }
            if (frow == 0) {
                int m_loc = wm * 128 + mt * 16 + fq * 4 + r;
                smB[wn * 256 + m_loc] = b;
                smI[wn * 256 + m_loc] = bi;
                smS[wn * 256 + m_loc] = s;
            }
        }
    }
    __syncthreads();
    if (tid < 256) {
        float b = smB[tid]; int bi = smI[tid]; float s = smS[tid];
        #pragma unroll
        for (int q = 1; q < 4; ++q) {
            float ob = smB[q * 256 + tid];
            int   oi = smI[q * 256 + tid];
            float os = smS[q * 256 + tid];
            bool take = ob < b;                // tie -> lower wn = lower cols
            float keep = take ? b : ob;
            b = take ? ob : b;
            bi = take ? oi : bi;
            s = fminf(fminf(s, os), keep);
        }
        size_t e = (size_t)blockIdx.y * M_TOK + (m0 + tid);
        candV[e] = b; candI[e] = bi; candS[e] = s;
    }
}

// ---------------------------------------------------------------------------
// reduce: fold 32 n-block candidates per row. Batched-8 independent candV
// loads; candS/candI read lazily only for the winning block (true global
// second = min(2nd-min over candV, candS[e*])). Packs (key|idx) u64 into
// rescueBuf; flagged rows get ~0 sentinel for rescue's atomicMin.
__global__ __launch_bounds__(64) void reduce_kernel(
    const float* __restrict__ candV, const int* __restrict__ candI,
    const float* __restrict__ candS,
    int* __restrict__ flagCnt, int* __restrict__ flagRows,
    u64* __restrict__ rescueBuf)
{
    int row = blockIdx.x * 64 + threadIdx.x;
    float best = 3.4e38f, second = 3.4e38f;
    int ebest = 0;
    #pragma unroll
    for (int e0 = 0; e0 < NBLK_N; e0 += 8) {
        float v[8];
        #pragma unroll
        for (int j = 0; j < 8; ++j) v[j] = candV[(size_t)(e0 + j) * M_TOK + row];
        #pragma unroll
        for (int j = 0; j < 8; ++j) {
            if (v[j] < best) { second = best; best = v[j]; ebest = e0 + j; }
            else second = fminf(second, v[j]);
        }
    }
    int bi = candI[(size_t)ebest * M_TOK + row];
    second = fminf(second, candS[(size_t)ebest * M_TOK + row]);
    u64 pk = ((u64)f2key(best) << 32) | (unsigned)bi;
    if (second - best < GAP_EPS) {
        pk = ~0ull;
        int k = atomicAdd(flagCnt, 1);
        flagRows[k] = row;
    }
    rescueBuf[row] = pk;
}

// ---------------------------------------------------------------------------
// rescue: exact fp32 argmin for flagged rows, grid-parallel in the code dim.
__global__ __launch_bounds__(256) void rescue_kernel(
    const float* __restrict__ X, const float* __restrict__ E,
    const float* __restrict__ esq,
    const int* __restrict__ flagCnt, const int* __restrict__ flagRows,
    u64* __restrict__ rescueBuf)
{
    __shared__ float xr[DIM];
    const int nwork = flagCnt[0] * (VOC / 256);
    for (int wk = blockIdx.x; wk < nwork; wk += gridDim.x) {
        int row = flagRows[wk >> 5];
        int c = ((wk & 31) << 8) + threadIdx.x;
        __syncthreads();
        xr[threadIdx.x] = X[(size_t)row * DIM + threadIdx.x];
        __syncthreads();
        const float4* er = (const float4*)(E + (size_t)c * DIM);
        float dot = 0.0f;
        #pragma unroll 8
        for (int k = 0; k < DIM / 4; ++k) {
            float4 e4 = er[k];
            float4 x4 = *(const float4*)&xr[k * 4];
            dot = fmaf(x4.x, e4.x, dot);
            dot = fmaf(x4.y, e4.y, dot);
            dot = fmaf(x4.z, e4.z, dot);
            dot = fmaf(x4.w, e4.w, dot);
        }
        float v = esq[c] - 2.0f * dot;
        u64 pk = ((u64)f2key(v) << 32) | (unsigned)c;
        atomicMin(&rescueBuf[row], pk);
    }
}

// ---------------------------------------------------------------------------
// assign: unpack code, write codes + quantize (STE), scatter counts/sums.
__global__ __launch_bounds__(256) void assign_kernel(
    const float* __restrict__ X, const float* __restrict__ E,
    const u64* __restrict__ rescueBuf,
    float* __restrict__ out_q, float* __restrict__ out_codes,
    float* __restrict__ counts, float* __restrict__ sums)
{
    int t = blockIdx.x * 4 + (threadIdx.x >> 6);
    int lane = threadIdx.x & 63;
    int code = (int)(unsigned)(rescueBuf[t] & 0xFFFFFFFFull);
    if (lane == 0) {
        out_codes[t] = (float)code;
        atomicAdd(&counts[code], 1.0f);
    }
    float4 x = *(const float4*)&X[(size_t)t * DIM + lane * 4];
    float4 e = *(const float4*)&E[(size_t)code * DIM + lane * 4];
    float4 q;
    q.x = x.x + (e.x - x.x);
    q.y = x.y + (e.y - x.y);
    q.z = x.z + (e.z - x.z);
    q.w = x.w + (e.w - x.w);
    *(float4*)&out_q[(size_t)t * DIM + lane * 4] = q;
    float* s = &sums[(size_t)code * DIM + lane * 4];
    atomicAdd(s + 0, x.x);
    atomicAdd(s + 1, x.y);
    atomicAdd(s + 2, x.z);
    atomicAdd(s + 3, x.w);
}

// ---------------------------------------------------------------------------
__global__ __launch_bounds__(256) void finalize_kernel(
    const float* __restrict__ cs, const float* __restrict__ ea,
    const float* __restrict__ counts, const float* __restrict__ sums,
    float* __restrict__ out_embed, float* __restrict__ out_cs,
    float* __restrict__ out_ea)
{
    int vd = blockIdx.x * 256 + threadIdx.x;
    int v = vd >> 8, d = vd & 255;
    float cnt = counts[v];
    float ncs = cs[v] * 0.99f + cnt * 0.01f;
    float cb  = sums[vd] * (1.0f / 2048.0f);
    float nea = ea[vd] * 0.99f + cb * 0.01f;
    out_ea[vd] = nea;
    out_embed[vd] = nea / (ncs + 1e-5f);
    if (d == 0) out_cs[v] = ncs;
}

// ---------------------------------------------------------------------------
extern "C" void kernel_launch(void* const* d_in, const int* in_sizes, int n_in,
                              void* d_out, int out_size, void* d_ws, size_t ws_size,
                              hipStream_t stream)
{
    const float* input     = (const float*)d_in[0];
    const float* embed     = (const float*)d_in[1];
    const float* cluster   = (const float*)d_in[2];
    const float* embed_avg = (const float*)d_in[3];

    float* out = (float*)d_out;
    float* ws  = (float*)d_ws;

    float* esq      = ws + WS_ESQ;
    int*   flagRows = (int*)(ws + WS_FLAGROWS);
    float* candV    = ws + WS_CANDV;
    int*   candI    = (int*)(ws + WS_CANDI);
    float* candS    = ws + WS_CANDS;
    u16*   Xhi      = (u16*)(ws + WS_XHI);
    u16*   Xlo      = (u16*)(ws + WS_XLO);
    u16*   Ehi      = (u16*)(ws + WS_EHI);
    u16*   Elo      = (u16*)(ws + WS_ELO);
    float* counts   = ws + WS_COUNTS;
    float* sums     = ws + WS_SUMS;
    int*   flagCnt  = (int*)(ws + WS_FLAGCNT);
    u64*   rescueBuf= (u64*)(ws + WS_RESCUE);   // aliases dead Xhi

    hipMemsetAsync((char*)d_ws + WS_ZERO_OFF_BYTES, 0, WS_ZERO_BYTES, stream);

    prep_kernel<<<(M_TOK + VOC) / 4, 256, 0, stream>>>(
        input, embed, Xhi, Xlo, Ehi, Elo, esq);

    dim3 g1(M_TOK / BM, VOC / BN);   // 64 x 32
    mfma_argmin_kernel<<<g1, 512, 0, stream>>>(
        Xhi, Xlo, Ehi, Elo, esq, candV, candI, candS);

    reduce_kernel<<<M_TOK / 64, 64, 0, stream>>>(
        candV, candI, candS, flagCnt, flagRows, rescueBuf);

    rescue_kernel<<<256, 256, 0, stream>>>(
        input, embed, esq, flagCnt, flagRows, rescueBuf);

    assign_kernel<<<M_TOK / 4, 256, 0, stream>>>(
        input, embed, rescueBuf, out + OUT_Q, out + OUT_C, counts, sums);

    finalize_kernel<<<(VOC * DIM) / 256, 256, 0, stream>>>(
        cluster, embed_avg, counts, sums,
        out + OUT_NE, out + OUT_NCS, out + OUT_NEA);
}

// Round 2
// 427.126 us; speedup vs baseline: 1.0816x; 1.0816x over previous
//
#include <hip/hip_runtime.h>
#include <math.h>

// Problem constants (fixed by setup_inputs)
#define M_TOK 16384   // B*T
#define DIM   256     // D (=K)
#define VOC   8192    // V (=N)

// GEMM tiling
#define BM 128
#define BN 128
#define BK 32
#define NBLK_N (VOC / BN)   // 64
#define GAP_EPS 0.01f       // rescue trigger; split-bf16 d2 err ~1e-4 << 0.01

typedef unsigned short u16;
typedef unsigned long long u64;
typedef __attribute__((ext_vector_type(8))) __bf16 bf16x8;
typedef __attribute__((ext_vector_type(4))) float f32x4;

// ---- workspace layout (float-element offsets) ------------------------------
#define WS_ESQ      0                     // [8192]
#define WS_FLAGROWS 24576                 // [16384] int
#define WS_CANDV    40960                 // [64][16384] f32
#define WS_CANDI    1089536               // [64][16384] int
#define WS_CANDS    2138112               // [64][16384] f32
#define WS_XHI      3186688               // [16384*256] bf16 (2097152 f32 slots)
#define WS_XLO      5283840
#define WS_EHI      7380992               // [8192*256] bf16 (1048576 slots)
#define WS_ELO      8429568
#define WS_COUNTS   9478144               // [8192]
#define WS_SUMS     9486336               // [8192*256]
#define WS_FLAGCNT  11583488              // [16] int
// rescueBuf [16384] u64 aliases Xhi (dead after mfma_argmin; reduce writes it)
#define WS_RESCUE   WS_XHI
#define WS_ZERO_OFF_BYTES ((size_t)WS_COUNTS * 4)
#define WS_ZERO_BYTES     ((size_t)(8192 + 2097152 + 16) * 4)

// ---- out layout (float-element offsets): quantize, codes, new_embed, new_cs, new_ea
#define OUT_Q   0
#define OUT_C   4194304
#define OUT_NE  4210688
#define OUT_NCS 6307840
#define OUT_NEA 6316032

__device__ inline u16 f2bf_rn(float x) {
    unsigned u = __float_as_uint(x);
    unsigned r = u + 0x7FFFu + ((u >> 16) & 1u);   // round-to-nearest-even
    return (u16)(r >> 16);
}
__device__ inline float bf2f(u16 u) { return __uint_as_float(((unsigned)u) << 16); }
__device__ inline unsigned f2key(float f) {          // order-preserving uint
    unsigned b = __float_as_uint(f);
    return (b & 0x80000000u) ? ~b : (b | 0x80000000u);
}

// ---------------------------------------------------------------------------
// prep: split X,E into bf16 hi/lo; compute esq from fp32 originals.
__global__ __launch_bounds__(256) void prep_kernel(
    const float* __restrict__ X, const float* __restrict__ E,
    u16* __restrict__ Xhi, u16* __restrict__ Xlo,
    u16* __restrict__ Ehi, u16* __restrict__ Elo,
    float* __restrict__ esq)
{
    int row  = blockIdx.x * 4 + (threadIdx.x >> 6);
    int lane = threadIdx.x & 63;
    bool isX = row < M_TOK;
    int r = isX ? row : row - M_TOK;
    const float* src = isX ? X + (size_t)row * DIM : E + (size_t)r * DIM;
    float4 v = ((const float4*)src)[lane];

    ushort4 h, lo;
    {
        u16 hb = f2bf_rn(v.x); h.x = hb; lo.x = f2bf_rn(v.x - bf2f(hb));
        hb = f2bf_rn(v.y); h.y = hb; lo.y = f2bf_rn(v.y - bf2f(hb));
        hb = f2bf_rn(v.z); h.z = hb; lo.z = f2bf_rn(v.z - bf2f(hb));
        hb = f2bf_rn(v.w); h.w = hb; lo.w = f2bf_rn(v.w - bf2f(hb));
    }
    u16* dh = isX ? Xhi : Ehi;
    u16* dl = isX ? Xlo : Elo;
    *(ushort4*)&dh[(size_t)r * DIM + lane * 4] = h;
    *(ushort4*)&dl[(size_t)r * DIM + lane * 4] = lo;

    if (!isX) {
        float s = v.x * v.x + v.y * v.y + v.z * v.z + v.w * v.w;
        #pragma unroll
        for (int o = 1; o < 64; o <<= 1) s += __shfl_xor(s, o, 64);
        if (lane == 0) esq[r] = s;
    }
}

// ---------------------------------------------------------------------------
// mfma_argmin (16x16x32, round-3 proven structure: ~242us, MfmaUtil ~40%):
// per 128x128 tile, dot = hi*hi + lo*hi + hi*lo (3 MFMAs per fragment pair),
// epilogue tracks per-row top-2 of (esq[n] - 2*dot).
// LDS staged via global_load_lds(16B) with XOR chunk swizzle (DMA forbids
// padding; swizzle keeps frag ds_read_b128 at <=2-way bank alias = free).
// Epilogue smB/I/S alias the dead tiles buffer (behind a __syncthreads) so
// LDS_Block_Size = 32768 exactly -> 5 blocks/CU (was 4): more resident waves
// to cover the per-K-step vmcnt0+barrier drain (m114-style implicit overlap).
__global__ __launch_bounds__(256, 2) void mfma_argmin_kernel(
    const u16* __restrict__ Xhi, const u16* __restrict__ Xlo,
    const u16* __restrict__ Ehi, const u16* __restrict__ Elo,
    const float* __restrict__ esq,
    float* __restrict__ candV, int* __restrict__ candI, float* __restrict__ candS)
{
    __shared__ __align__(16) char tiles[4 * 8192];   // Ahi, Alo, Bhi, Blo

    const int tid = threadIdx.x;
    const int w = tid >> 6, l = tid & 63;
    const int wy = w >> 1, wx = w & 1;
    const int m0 = blockIdx.x * BM;
    const int n0 = blockIdx.y * BN;

    f32x4 acc[4][4];
    #pragma unroll
    for (int i = 0; i < 4; ++i)
        #pragma unroll
        for (int j = 0; j < 4; ++j) acc[i][j] = (f32x4)0.0f;

    // staging: wave w stages tile w (0=Ahi 1=Alo 2=Bhi 3=Blo)
    const u16* gbase;
    int row0;
    if (w == 0)      { gbase = Xhi; row0 = m0; }
    else if (w == 1) { gbase = Xlo; row0 = m0; }
    else if (w == 2) { gbase = Ehi; row0 = n0; }
    else             { gbase = Elo; row0 = n0; }
    const int swz_c = (l & 3) ^ ((l >> 3) & 3);
    const u16* gsrc0 = gbase + (size_t)(row0 + (l >> 2)) * DIM + swz_c * 8;
    char* ltile = tiles + w * 8192;

    const int frow = l & 15, fq = l >> 4;
    const int fs = ((fq ^ ((frow >> 1) & 3)) * 16);
    const char* aHiP = tiles + 0 * 8192 + (wy * 64 + frow) * 64 + fs;
    const char* aLoP = tiles + 1 * 8192 + (wy * 64 + frow) * 64 + fs;
    const char* bHiP = tiles + 2 * 8192 + (wx * 64 + frow) * 64 + fs;
    const char* bLoP = tiles + 3 * 8192 + (wx * 64 + frow) * 64 + fs;

    for (int ks = 0; ks < DIM / BK; ++ks) {
        const int k0 = ks * BK;
        __syncthreads();
        #pragma unroll
        for (int i = 0; i < 8; ++i) {
            __builtin_amdgcn_global_load_lds(
                (const __attribute__((address_space(1))) unsigned int*)(gsrc0 + (size_t)i * 16 * DIM + k0),
                (__attribute__((address_space(3))) unsigned int*)(ltile + i * 1024),
                16, 0, 0);
        }
        __syncthreads();

        bf16x8 ah[4], al[4];
        #pragma unroll
        for (int mt = 0; mt < 4; ++mt) {
            ah[mt] = *(const bf16x8*)(aHiP + mt * 1024);
            al[mt] = *(const bf16x8*)(aLoP + mt * 1024);
        }
        #pragma unroll
        for (int nt = 0; nt < 4; ++nt) {
            bf16x8 bh = *(const bf16x8*)(bHiP + nt * 1024);
            bf16x8 bl = *(const bf16x8*)(bLoP + nt * 1024);
            #pragma unroll
            for (int mt = 0; mt < 4; ++mt) {
                acc[mt][nt] = __builtin_amdgcn_mfma_f32_16x16x32_bf16(ah[mt], bh, acc[mt][nt], 0, 0, 0);
                acc[mt][nt] = __builtin_amdgcn_mfma_f32_16x16x32_bf16(al[mt], bh, acc[mt][nt], 0, 0, 0);
                acc[mt][nt] = __builtin_amdgcn_mfma_f32_16x16x32_bf16(ah[mt], bl, acc[mt][nt], 0, 0, 0);
            }
        }
    }

    // tiles are dead from here; re-use for the cross-wave reduce arrays
    __syncthreads();
    float* smB = (float*)tiles;            // [2][128]
    int*   smI = (int*)(tiles + 1024);     // [2][128]
    float* smS = (float*)(tiles + 2048);   // [2][128]

    // epilogue: per-row top-2 argmin of val = esq[n] - 2*dot
    float eq[4];
    #pragma unroll
    for (int nt = 0; nt < 4; ++nt) eq[nt] = esq[n0 + wx * 64 + nt * 16 + frow];

    #pragma unroll
    for (int mt = 0; mt < 4; ++mt) {
        #pragma unroll
        for (int r = 0; r < 4; ++r) {
            float b = 3.4e38f, s = 3.4e38f;
            int bi = 0;
            #pragma unroll
            for (int nt = 0; nt < 4; ++nt) {
                float v = fmaf(-2.0f, acc[mt][nt][r], eq[nt]);
                int col = n0 + wx * 64 + nt * 16 + frow;
                if (v < b) { s = b; b = v; bi = col; }
                else if (v < s) s = v;
            }
            #pragma unroll
            for (int o = 1; o < 16; o <<= 1) {
                float ob = __shfl_xor(b, o, 64);
                int   oi = __shfl_xor(bi, o, 64);
                float os = __shfl_xor(s, o, 64);
                bool take = (ob < b) || (ob == b && oi < bi);
                float keep = take ? b : ob;
                b  = take ? ob : b;
                bi = take ? oi : bi;
                s  = fminf(fminf(s, os), keep);
            }
            if (frow == 0) {
                int m_loc = wy * 64 + mt * 16 + fq * 4 + r;
                smB[wx * 128 + m_loc] = b;
                smI[wx * 128 + m_loc] = bi;
                smS[wx * 128 + m_loc] = s;
            }
        }
    }
    __syncthreads();
    if (tid < 128) {
        float b0 = smB[tid],       b1 = smB[128 + tid];
        int   i0 = smI[tid],       i1 = smI[128 + tid];
        float s0 = smS[tid],       s1 = smS[128 + tid];
        bool take = (b1 < b0);                 // tie -> wave 0 (lower cols)
        float b = take ? b1 : b0;
        int  bi = take ? i1 : i0;
        float s = fminf(fminf(s0, s1), take ? b0 : b1);
        size_t e = (size_t)blockIdx.y * M_TOK + (m0 + tid);
        candV[e] = b; candI[e] = bi; candS[e] = s;
    }
}

// ---------------------------------------------------------------------------
// reduce: fold 64 n-block candidates per row. Batched-8 independent candV
// loads; candS/candI read lazily only for the winning block (true global
// second = min(2nd-min over candV, candS[e*])). Packs (key|idx) u64 into
// rescueBuf; flagged rows get ~0 sentinel for rescue's atomicMin.
__global__ __launch_bounds__(64) void reduce_kernel(
    const float* __restrict__ candV, const int* __restrict__ candI,
    const float* __restrict__ candS,
    int* __restrict__ flagCnt, int* __restrict__ flagRows,
    u64* __restrict__ rescueBuf)
{
    int row = blockIdx.x * 64 + threadIdx.x;
    float best = 3.4e38f, second = 3.4e38f;
    int ebest = 0;
    #pragma unroll
    for (int e0 = 0; e0 < NBLK_N; e0 += 8) {
        float v[8];
        #pragma unroll
        for (int j = 0; j < 8; ++j) v[j] = candV[(size_t)(e0 + j) * M_TOK + row];
        #pragma unroll
        for (int j = 0; j < 8; ++j) {
            if (v[j] < best) { second = best; best = v[j]; ebest = e0 + j; }
            else second = fminf(second, v[j]);
        }
    }
    int bi = candI[(size_t)ebest * M_TOK + row];
    second = fminf(second, candS[(size_t)ebest * M_TOK + row]);
    u64 pk = ((u64)f2key(best) << 32) | (unsigned)bi;
    if (second - best < GAP_EPS) {
        pk = ~0ull;
        int k = atomicAdd(flagCnt, 1);
        flagRows[k] = row;
    }
    rescueBuf[row] = pk;
}

// ---------------------------------------------------------------------------
// rescue: exact fp32 argmin for flagged rows. BATCHED: each work item is
// (group of 8 flagged rows, 256-code chunk). xr[8][256] staged in LDS; the
// inner fma reads xr with wave-uniform addresses (LDS broadcast = free), so
// E-chunk traffic drops 8x vs the per-row version (the old kernel re-read
// the full 8MB codebook from L2 per flagged row: ~6.4GB at ~800 rows, ~185us
// at the L2 ceiling -> now compute-bound ~25-40us).
// Winner via per-wave u64 shuffle-min then one atomicMin per (wave,row).
// Grid-stride keeps (wk & 31) invariant per block (stride 1024 % 32 == 0) so
// each block stays on one E-chunk -> L2-resident.
__global__ __launch_bounds__(256) void rescue_kernel(
    const float* __restrict__ X, const float* __restrict__ E,
    const float* __restrict__ esq,
    const int* __restrict__ flagCnt, const int* __restrict__ flagRows,
    u64* __restrict__ rescueBuf)
{
    __shared__ float xr[8][DIM];
    __shared__ int rowids[8];
    const int nflag = flagCnt[0];
    const int ngroups = (nflag + 7) >> 3;
    const int nwork = ngroups * 32;
    const int lane = threadIdx.x & 63;

    for (int wk = blockIdx.x; wk < nwork; wk += gridDim.x) {
        const int g = wk >> 5, chunk = wk & 31;
        __syncthreads();                       // protect xr/rowids reuse
        if (threadIdx.x < 8) {
            int idx = g * 8 + threadIdx.x;
            rowids[threadIdx.x] = (idx < nflag) ? flagRows[idx] : -1;
        }
        {
            int i = threadIdx.x >> 5;          // row slot 0..7
            int idx = g * 8 + i;
            int row = flagRows[(idx < nflag) ? idx : (nflag - 1)];
            const float4* src = (const float4*)(X + (size_t)row * DIM);
            int c4 = (threadIdx.x & 31) * 2;
            ((float4*)xr[i])[c4]     = src[c4];
            ((float4*)xr[i])[c4 + 1] = src[c4 + 1];
        }
        __syncthreads();

        const int c = (chunk << 8) + threadIdx.x;
        const float4* er = (const float4*)(E + (size_t)c * DIM);
        float dot[8];
        #pragma unroll
        for (int i = 0; i < 8; ++i) dot[i] = 0.0f;
        #pragma unroll 4
        for (int k = 0; k < DIM / 4; ++k) {
            float4 e4 = er[k];
            #pragma unroll
            for (int i = 0; i < 8; ++i) {
                float4 x4 = ((const float4*)xr[i])[k];   // wave-uniform: broadcast
                dot[i] = fmaf(x4.x, e4.x, dot[i]);
                dot[i] = fmaf(x4.y, e4.y, dot[i]);
                dot[i] = fmaf(x4.z, e4.z, dot[i]);
                dot[i] = fmaf(x4.w, e4.w, dot[i]);
            }
        }
        float eq = esq[c];
        #pragma unroll
        for (int i = 0; i < 8; ++i) {
            float v = fmaf(-2.0f, dot[i], eq);
            u64 pk = ((u64)f2key(v) << 32) | (unsigned)c;
            #pragma unroll
            for (int o = 1; o < 64; o <<= 1) {
                u64 other = __shfl_xor(pk, o, 64);
                pk = (other < pk) ? other : pk;
            }
            if (lane == 0 && g * 8 + i < nflag)
                atomicMin(&rescueBuf[rowids[i]], pk);
        }
    }
}

// ---------------------------------------------------------------------------
// assign: unpack code, write codes + quantize (STE), scatter counts/sums.
__global__ __launch_bounds__(256) void assign_kernel(
    const float* __restrict__ X, const float* __restrict__ E,
    const u64* __restrict__ rescueBuf,
    float* __restrict__ out_q, float* __restrict__ out_codes,
    float* __restrict__ counts, float* __restrict__ sums)
{
    int t = blockIdx.x * 4 + (threadIdx.x >> 6);
    int lane = threadIdx.x & 63;
    int code = (int)(unsigned)(rescueBuf[t] & 0xFFFFFFFFull);
    if (lane == 0) {
        out_codes[t] = (float)code;
        atomicAdd(&counts[code], 1.0f);
    }
    float4 x = *(const float4*)&X[(size_t)t * DIM + lane * 4];
    float4 e = *(const float4*)&E[(size_t)code * DIM + lane * 4];
    float4 q;
    q.x = x.x + (e.x - x.x);
    q.y = x.y + (e.y - x.y);
    q.z = x.z + (e.z - x.z);
    q.w = x.w + (e.w - x.w);
    *(float4*)&out_q[(size_t)t * DIM + lane * 4] = q;
    float* s = &sums[(size_t)code * DIM + lane * 4];
    atomicAdd(s + 0, x.x);
    atomicAdd(s + 1, x.y);
    atomicAdd(s + 2, x.z);
    atomicAdd(s + 3, x.w);
}

// ---------------------------------------------------------------------------
__global__ __launch_bounds__(256) void finalize_kernel(
    const float* __restrict__ cs, const float* __restrict__ ea,
    const float* __restrict__ counts, const float* __restrict__ sums,
    float* __restrict__ out_embed, float* __restrict__ out_cs,
    float* __restrict__ out_ea)
{
    int vd = blockIdx.x * 256 + threadIdx.x;
    int v = vd >> 8, d = vd & 255;
    float cnt = counts[v];
    float ncs = cs[v] * 0.99f + cnt * 0.01f;
    float cb  = sums[vd] * (1.0f / 2048.0f);
    float nea = ea[vd] * 0.99f + cb * 0.01f;
    out_ea[vd] = nea;
    out_embed[vd] = nea / (ncs + 1e-5f);
    if (d == 0) out_cs[v] = ncs;
}

// ---------------------------------------------------------------------------
extern "C" void kernel_launch(void* const* d_in, const int* in_sizes, int n_in,
                              void* d_out, int out_size, void* d_ws, size_t ws_size,
                              hipStream_t stream)
{
    const float* input     = (const float*)d_in[0];
    const float* embed     = (const float*)d_in[1];
    const float* cluster   = (const float*)d_in[2];
    const float* embed_avg = (const float*)d_in[3];

    float* out = (float*)d_out;
    float* ws  = (float*)d_ws;

    float* esq      = ws + WS_ESQ;
    int*   flagRows = (int*)(ws + WS_FLAGROWS);
    float* candV    = ws + WS_CANDV;
    int*   candI    = (int*)(ws + WS_CANDI);
    float* candS    = ws + WS_CANDS;
    u16*   Xhi      = (u16*)(ws + WS_XHI);
    u16*   Xlo      = (u16*)(ws + WS_XLO);
    u16*   Ehi      = (u16*)(ws + WS_EHI);
    u16*   Elo      = (u16*)(ws + WS_ELO);
    float* counts   = ws + WS_COUNTS;
    float* sums     = ws + WS_SUMS;
    int*   flagCnt  = (int*)(ws + WS_FLAGCNT);
    u64*   rescueBuf= (u64*)(ws + WS_RESCUE);   // aliases dead Xhi

    hipMemsetAsync((char*)d_ws + WS_ZERO_OFF_BYTES, 0, WS_ZERO_BYTES, stream);

    prep_kernel<<<(M_TOK + VOC) / 4, 256, 0, stream>>>(
        input, embed, Xhi, Xlo, Ehi, Elo, esq);

    dim3 g1(M_TOK / BM, VOC / BN);
    mfma_argmin_kernel<<<g1, 256, 0, stream>>>(
        Xhi, Xlo, Ehi, Elo, esq, candV, candI, candS);

    reduce_kernel<<<M_TOK / 64, 64, 0, stream>>>(
        candV, candI, candS, flagCnt, flagRows, rescueBuf);

    rescue_kernel<<<1024, 256, 0, stream>>>(
        input, embed, esq, flagCnt, flagRows, rescueBuf);

    assign_kernel<<<M_TOK / 4, 256, 0, stream>>>(
        input, embed, rescueBuf, out + OUT_Q, out + OUT_C, counts, sums);

    finalize_kernel<<<(VOC * DIM) / 256, 256, 0, stream>>>(
        cluster, embed_avg, counts, sums,
        out + OUT_NE, out + OUT_NCS, out + OUT_NEA);
}